// Round 3
// baseline (878.576 us; speedup 1.0000x reference)
//
#include <hip/hip_runtime.h>

// GraphDiTPolicy fused kernel for MI355X (gfx950).
// B=32768, N=2, T=4, D=256, H=8, E=2, HD=32, S=8. Output FP32.
//
// Round 6 (theory: the pooled-stash + separate proj_kernel cost ~300us:
// WRITE_SIZE pinned at 4x out-buffer regardless of stash layout, cross-XCD
// dirty-line RT, 268MB aggregate WoT re-reads, NT scattered stores):
//  - proj_kernel ELIMINATED. Out-projection accumulated per head inside
//    fused: out = sum_h pooled[:, h*32:+32] @ Wo[h*32:+32, :]. Per head the
//    32x32 pooled slice is exchanged via new LDS slab ps[32][40] (2.5KB,
//    total LDS 40448 <= 40960 -> still 4 blocks/CU), then one K=32 MFMA
//    step (8 MFMA/wave) accumulates into persistent fo[2][4].
//  - Wo B-fragments prefetched per head right after the QKV loop (latency
//    hides under epilogue+attention).
//  - final out written once, plain fp32 stores (round-3-proven 66MB clean).
//  - barrier safety: ps at bytes 37888..40447, above the 24576B staging
//    window; write ps -> syncthreads -> read; the next head's top barrier
//    orders rewrites after all readers.

typedef short bf16x8 __attribute__((ext_vector_type(8)));
typedef float f32x4 __attribute__((ext_vector_type(4)));
typedef unsigned short u16;

#define SCALE_F 0.17677669529663687f   // 1/sqrt(32)
#define WT_BYTES (1024 * 256 * 2)      // (768+256) rows x 256 cols x 2B

__device__ __forceinline__ float bf2f(u16 h) {
  unsigned u = ((unsigned)h) << 16; float f; __builtin_memcpy(&f, &u, 4); return f;
}
__device__ __forceinline__ u16 f2bf(float f) {
  unsigned u; __builtin_memcpy(&u, &f, 4);
  u += 0x7FFFu + ((u >> 16) & 1u);
  return (u16)(u >> 16);
}
__device__ __forceinline__ float fast_tanh(float x) {
  float e = __expf(2.0f * x);
  return (e - 1.0f) / (e + 1.0f);
}

template<bool F32>
__device__ __forceinline__ float LD(const void* p, int i) {
  if constexpr (F32) return ((const float*)p)[i];
  else return bf2f(((const u16*)p)[i]);
}

// nontemporal 8-value bf16 A-fragment load (x is streamed once, no reuse)
template<bool F32>
__device__ __forceinline__ bf16x8 load8bf_nt(const void* p, int idx) {
  if constexpr (F32) {
    const f32x4* f = (const f32x4*)((const float*)p + idx);
    f32x4 a = __builtin_nontemporal_load(f);
    f32x4 b = __builtin_nontemporal_load(f + 1);
    bf16x8 r;
    r[0] = (short)f2bf(a[0]); r[1] = (short)f2bf(a[1]);
    r[2] = (short)f2bf(a[2]); r[3] = (short)f2bf(a[3]);
    r[4] = (short)f2bf(b[0]); r[5] = (short)f2bf(b[1]);
    r[6] = (short)f2bf(b[2]); r[7] = (short)f2bf(b[3]);
    return r;
  } else {
    return __builtin_nontemporal_load((const bf16x8*)((const u16*)p + idx));
  }
}

// async 16B global -> LDS (dest = wave-uniform base + lane*16)
__device__ __forceinline__ void gl_lds16(const u16* g, u16* l) {
  __builtin_amdgcn_global_load_lds(
      (const __attribute__((address_space(1))) unsigned int*)g,
      (__attribute__((address_space(3))) unsigned int*)l, 16, 0, 0);
}

// ---------------- prep: transpose weights to WT, compute dtype flag ----------
// WT[n][k'] rows 0-767 = {Wq,Wk,Wv} columns, XOR-pre-swizzled: k' = k ^ ((n&7)<<3)
// rows 768-1023 = Wo columns, UNswizzled (read as B-fragments directly).
__global__ void prep_kernel(const u16* __restrict__ x16,
                            const void* __restrict__ Wq, const void* __restrict__ Wk,
                            const void* __restrict__ Wv, const void* __restrict__ Wo,
                            int* __restrict__ flag, u16* __restrict__ WT) {
  __shared__ int tot;
  if (threadIdx.x == 0) tot = 0;
  __syncthreads();
  int cnt = 0;
  for (int i = threadIdx.x; i < 4096; i += 256) {
    int e = (x16[2 * i] >> 7) & 0xFF;
    cnt += (e >= 0x90 || e <= 0x50) ? 1 : 0;
  }
  atomicAdd(&tot, cnt);
  __syncthreads();
  const bool f32 = (tot >= 64);
  if (blockIdx.x == 0 && threadIdx.x == 0) *flag = f32 ? 1 : 0;

  int n = blockIdx.x;
  int k = threadIdx.x;
  if (n < 768) {
    int sel = n >> 8, col = n & 255;
    const void* src = sel == 0 ? Wq : (sel == 1 ? Wk : Wv);
    float v = f32 ? ((const float*)src)[k * 256 + col] : bf2f(((const u16*)src)[k * 256 + col]);
    WT[n * 256 + (k ^ ((n & 7) << 3))] = f2bf(v);
  } else {
    int col = n - 768;
    float v = f32 ? ((const float*)Wo)[k * 256 + col] : bf2f(((const u16*)Wo)[k * 256 + col]);
    WT[768 * 256 + col * 256 + k] = f2bf(v);
  }
}

// ---------------- main fused kernel -----------------------------------------
struct __align__(16) Scratch {
  u16 qk[4][32][72];    // [wave][xrow][Q 0-31 | K 32-63 | pad]          18432 B
  u16 vt[4][32][56];    // [wave][d][xrow]; cols>=32 don't-care          14336 B
  u16 pb[4][16][40];    // [wave][s'][t]; cols 16-31 MUST be 0            5120 B
  u16 ps[32][40];       // per-head pooled slice [block row][k0..31|pad]  2560 B
};
union SharedU {
  u16 wtile[2][6144];   // 2 x (96 rows x 64 cols) = 2 x 12288 B staging window
  Scratch s;            // 40448 B total LDS -> 4 blocks/CU (160KB)
};

template<bool F32>
__device__ __forceinline__ void fused_impl(
    SharedU& sm,
    const void* __restrict__ x, const void* __restrict__ edge,
    const void* __restrict__ bq, const void* __restrict__ bk, const void* __restrict__ bv,
    const void* __restrict__ bo,
    const void* __restrict__ Wbias, const void* __restrict__ bbias,
    const void* __restrict__ Wgate, const void* __restrict__ bgate,
    const void* __restrict__ Wscale, const void* __restrict__ bscale,
    const void* __restrict__ Wshift, const void* __restrict__ bshift,
    const void* __restrict__ Whs, const void* __restrict__ bhs,
    const u16* __restrict__ WT, float* __restrict__ out) {
  const int tid = threadIdx.x;
  const int w  = tid >> 6;     // wave 0..3, owns batches w*4..w*4+3
  const int l  = tid & 63;
  const int ln = l & 15;
  const int q4 = l >> 4;       // quad group 0..3
  const u16* WoT = WT + 768 * 256;

  // one-time zero: vt (all; pads must stay finite) + pb (cols 16-31 pad).
  // pb at bytes 32768..37887, ps at 37888..40447: both above the 24576B
  // staging window -> never clobbered by staging.
  {
    u16* vz = &sm.s.vt[w][0][0];
#pragma unroll
    for (int i = 0; i < 28; ++i) vz[l + 64 * i] = 0;   // 32*56 = 1792
    u16* pz = &sm.s.pb[w][0][0];
#pragma unroll
    for (int i = 0; i < 10; ++i) pz[l + 64 * i] = 0;   // 16*40 = 640
  }

  // edge preload (constant indices only -> stays in VGPRs)
  float eA[4], eB[4];
#pragma unroll
  for (int i = 0; i < 4; ++i) {
    int gb = blockIdx.x * 16 + w * 4 + i;
    eA[i] = LD<F32>(edge, gb * 2);
    eB[i] = LD<F32>(edge, gb * 2 + 1);
  }

  // X rows as MFMA A-fragments: lane holds X[mt*16+ln][ks*32 + q4*8 + j]
  const int xbase = (blockIdx.x * 128 + w * 32) * 256;
  bf16x8 xa[2][8];
#pragma unroll
  for (int mt = 0; mt < 2; ++mt)
#pragma unroll
    for (int ks = 0; ks < 8; ++ks)
      xa[mt][ks] = load8bf_nt<F32>(x, xbase + (mt * 16 + ln) * 256 + ks * 32 + q4 * 8);

  // per-lane staging source bases: staged row r = i*32 + w*8 + (l>>3),
  // global WT row ng = ((r>>5)<<8) + h*32 + (r&31); col (l&7)*8 within quarter
  const u16* wsrc[3];
#pragma unroll
  for (int i = 0; i < 3; ++i) {
    int r = i * 32 + w * 8 + (l >> 3);
    int ngb = ((r >> 5) << 8) + (r & 31);
    wsrc[i] = WT + ngb * 256 + (l & 7) * 8;
  }
  // head-independent LDS fragment addressing (quarter layout: 64-col rows)
  int rowoff[6];
#pragma unroll
  for (int nt = 0; nt < 6; ++nt)
    rowoff[nt] = ((nt >> 1) * 32 + (nt & 1) * 16 + ln) * 64;
  const int swz = (ln & 7) << 3;   // matches prep's pre-swizzle ((n&7)<<3)

  // persistent out-projection accumulators: rows mt*16+q4*4+r, cols w*64+ntw*16+ln
  f32x4 fo[2][4];
#pragma unroll
  for (int mt = 0; mt < 2; ++mt)
#pragma unroll
    for (int nt = 0; nt < 4; ++nt) fo[mt][nt] = (f32x4){0.f, 0.f, 0.f, 0.f};

#pragma unroll 1
  for (int h = 0; h < 8; ++h) {
    // ---------- QKV GEMM head h: [32 rows] x [96 cols] x K=256 ----------
    f32x4 acc[2][6];
#pragma unroll
    for (int mt = 0; mt < 2; ++mt)
#pragma unroll
      for (int nt = 0; nt < 6; ++nt) acc[mt][nt] = (f32x4){0.f, 0.f, 0.f, 0.f};

    __syncthreads();   // prev head fully done with aliased scratch + ps reads
#pragma unroll
    for (int i = 0; i < 3; ++i)
      gl_lds16(wsrc[i] + h * 8192, &sm.wtile[0][(i * 32 + w * 8) * 64]);
    __syncthreads();   // quarter 0 staged & visible
#pragma unroll
    for (int q = 0; q < 4; ++q) {
      if (q < 3) {     // prefetch next quarter into the other buffer
#pragma unroll
        for (int i = 0; i < 3; ++i)
          gl_lds16(wsrc[i] + h * 8192 + (q + 1) * 64,
                   &sm.wtile[(q + 1) & 1][(i * 32 + w * 8) * 64]);
      }
#pragma unroll
      for (int k2 = 0; k2 < 2; ++k2) {
        int cx = (k2 * 32 + q4 * 8) ^ swz;
        const u16* wq = &sm.wtile[q & 1][0];
#pragma unroll
        for (int nt = 0; nt < 6; ++nt) {
          bf16x8 bfr = *(const bf16x8*)(wq + rowoff[nt] + cx);
          acc[0][nt] = __builtin_amdgcn_mfma_f32_16x16x32_bf16(xa[0][q * 2 + k2], bfr, acc[0][nt], 0, 0, 0);
          acc[1][nt] = __builtin_amdgcn_mfma_f32_16x16x32_bf16(xa[1][q * 2 + k2], bfr, acc[1][nt], 0, 0, 0);
        }
      }
      __syncthreads();  // staged q+1 visible; epilogue must not clobber wtile
    }

    // Wo B-fragments for this head's out-proj step: prefetch NOW so the
    // ~L2 latency hides under epilogue + attention.
    bf16x8 wob[4];
#pragma unroll
    for (int ntw = 0; ntw < 4; ++ntw)
      wob[ntw] = *(const bf16x8*)(WoT + (w * 64 + ntw * 16 + ln) * 256 + h * 32 + q4 * 8);

    // ---------- epilogue: Q,K (+bias) row-major to LDS ----------
#pragma unroll
    for (int nt = 0; nt < 4; ++nt) {
      int cb = (nt & 1) * 16 + ln;                       // 0..31 within head
      float bias = LD<F32>((nt >> 1) ? bk : bq, h * 32 + cb);
      int col = (nt >> 1) * 32 + cb;                     // Q: 0-31, K: 32-63
#pragma unroll
      for (int mt = 0; mt < 2; ++mt)
#pragma unroll
        for (int r = 0; r < 4; ++r)
          sm.s.qk[w][mt * 16 + q4 * 4 + r][col] = f2bf(acc[mt][nt][r] + bias);
    }
    // ---------- epilogue: V with edge modulation, stored transposed ----------
#pragma unroll
    for (int nt = 4; nt < 6; ++nt) {
      int dg = h * 32 + (nt - 4) * 16 + ln;              // global dim
      float bvv = LD<F32>(bv, dg);
      float wg0 = LD<F32>(Wgate, dg),  wg1 = LD<F32>(Wgate, 256 + dg),  bg  = LD<F32>(bgate, dg);
      float ws0 = LD<F32>(Wscale, dg), ws1 = LD<F32>(Wscale, 256 + dg), bs  = LD<F32>(bscale, dg);
      float wf0 = LD<F32>(Wshift, dg), wf1 = LD<F32>(Wshift, 256 + dg), bsh = LD<F32>(bshift, dg);
#pragma unroll
      for (int mt = 0; mt < 2; ++mt) {
        float e0 = (q4 & 2) ? eA[mt * 2 + 1] : eA[mt * 2];
        float e1 = (q4 & 2) ? eB[mt * 2 + 1] : eB[mt * 2];
        float ga = 1.f / (1.f + __expf(-(e0 * wg0 + e1 * wg1 + bg)));
        float sc = fast_tanh(e0 * ws0 + e1 * ws1 + bs);
        float sh = e0 * wf0 + e1 * wf1 + bsh;
        u16 vv[4];
#pragma unroll
        for (int r = 0; r < 4; ++r) {
          float v = acc[mt][nt][r] + bvv;
          v = (v * (1.f + sc) + sh) * ga;
          vv[r] = f2bf(v);
        }
        ushort4 pk; pk.x = vv[0]; pk.y = vv[1]; pk.z = vv[2]; pk.w = vv[3];
        *(ushort4*)&sm.s.vt[w][(nt - 4) * 16 + ln][mt * 16 + q4 * 4] = pk;
      }
    }
    __asm__ volatile("" ::: "memory");  // wave-private LDS; DS ops in-order

    // ---------- attention: 2 batches packed per 16x16 tile ----------
    float wb0 = LD<F32>(Wbias, h), wb1 = LD<F32>(Wbias, 8 + h), bb  = LD<F32>(bbias, h);
    float wh0 = LD<F32>(Whs, h),   wh1 = LD<F32>(Whs, 8 + h),   bh_ = LD<F32>(bhs, h);
#pragma unroll
    for (int pair = 0; pair < 2; ++pair) {
      bf16x8 qa = *(const bf16x8*)&sm.s.qk[w][pair * 16 + ln][q4 * 8];       // Q rows
      bf16x8 kb = *(const bf16x8*)&sm.s.qk[w][pair * 16 + ln][32 + q4 * 8];  // K rows
      f32x4 z4 = {0.f, 0.f, 0.f, 0.f};
      f32x4 s = __builtin_amdgcn_mfma_f32_16x16x32_bf16(qa, kb, z4, 0, 0, 0);

      float e00 = eA[pair * 2],     e01 = eB[pair * 2];
      float e10 = eA[pair * 2 + 1], e11 = eB[pair * 2 + 1];
      float eb0 = e00 * wb0 + e01 * wb1 + bb;
      float eb1 = e10 * wb0 + e11 * wb1 + bb;
      float hs0 = fast_tanh(e00 * wh0 + e01 * wh1 + bh_);
      float hs1 = fast_tanh(e10 * wh0 + e11 * wh1 + bh_);
      int bj = ln >> 3;                       // column batch within pair
      float mult = SCALE_F * (1.f + (bj ? hs1 : hs0));
      float ebias = bj ? eb1 : eb0;
      int tl = ln & 7;
      bool valid = ((q4 >> 1) == bj);         // row batch == col batch
      float p[4];
#pragma unroll
      for (int r = 0; r < 4; ++r) {
        int sl = (q4 & 1) * 4 + r;            // s within batch
        p[r] = s[r] * mult + ((tl == (sl ^ 4)) ? ebias : 0.f);  // sparse bias
      }
      // softmax over t (8-lane groups)
#pragma unroll
      for (int r = 0; r < 4; ++r) {
        float m = p[r];
        m = fmaxf(m, __shfl_xor(m, 1));
        m = fmaxf(m, __shfl_xor(m, 2));
        m = fmaxf(m, __shfl_xor(m, 4));
        float e = __expf(p[r] - m);
        float su = e;
        su += __shfl_xor(su, 1);
        su += __shfl_xor(su, 2);
        su += __shfl_xor(su, 4);
        p[r] = e / su;
      }
#pragma unroll
      for (int r = 0; r < 4; ++r)
        sm.s.pb[w][q4 * 4 + r][ln] = valid ? f2bf(p[r]) : (u16)0;
      __asm__ volatile("" ::: "memory");

      // P.V via MFMA; lane's 4 C rows = one (batch,node)'s T rows -> free mean
      bf16x8 pa = *(const bf16x8*)&sm.s.pb[w][ln][q4 * 8];
#pragma unroll
      for (int nt = 0; nt < 2; ++nt) {
        bf16x8 vb = *(const bf16x8*)&sm.s.vt[w][nt * 16 + ln][pair * 16 + q4 * 8];
        f32x4 z = {0.f, 0.f, 0.f, 0.f};
        f32x4 o = __builtin_amdgcn_mfma_f32_16x16x32_bf16(pa, vb, z, 0, 0, 0);
        float pm = (o[0] + o[1] + o[2] + o[3]) * 0.25f;   // mean over T=4
        int prow = w * 8 + (pair * 2 + (q4 >> 1)) * 2 + (q4 & 1);
        sm.s.ps[prow][nt * 16 + ln] = f2bf(pm);           // head-local k col
      }
    }

    // ---------- out-projection accumulate: fo += ps(32x32) @ Wo-slice ----------
    __syncthreads();   // all waves' ps writes visible
    {
      bf16x8 pa0 = *(const bf16x8*)&sm.s.ps[ln][q4 * 8];
      bf16x8 pa1 = *(const bf16x8*)&sm.s.ps[16 + ln][q4 * 8];
#pragma unroll
      for (int ntw = 0; ntw < 4; ++ntw) {
        fo[0][ntw] = __builtin_amdgcn_mfma_f32_16x16x32_bf16(pa0, wob[ntw], fo[0][ntw], 0, 0, 0);
        fo[1][ntw] = __builtin_amdgcn_mfma_f32_16x16x32_bf16(pa1, wob[ntw], fo[1][ntw], 0, 0, 0);
      }
    }
    // next head's top barrier orders ps rewrite after all readers
  }

  // ---------- final store: out = fo + bo (fp32, plain stores) ----------
#pragma unroll
  for (int ntw = 0; ntw < 4; ++ntw) {
    int col = w * 64 + ntw * 16 + ln;
    float bias = LD<F32>(bo, col);
#pragma unroll
    for (int mt = 0; mt < 2; ++mt)
#pragma unroll
      for (int r = 0; r < 4; ++r) {
        int row = mt * 16 + q4 * 4 + r;       // block-local batch*2+node
        out[(blockIdx.x * 32 + row) * 256 + col] = fo[mt][ntw][r] + bias;
      }
  }
}

__global__ __launch_bounds__(256, 4) void fused_kernel(
    const void* __restrict__ x, const void* __restrict__ edge,
    const void* __restrict__ bq, const void* __restrict__ bk, const void* __restrict__ bv,
    const void* __restrict__ bo,
    const void* __restrict__ Wbias, const void* __restrict__ bbias,
    const void* __restrict__ Wgate, const void* __restrict__ bgate,
    const void* __restrict__ Wscale, const void* __restrict__ bscale,
    const void* __restrict__ Wshift, const void* __restrict__ bshift,
    const void* __restrict__ Whs, const void* __restrict__ bhs,
    const int* __restrict__ flag, const u16* __restrict__ WT, float* __restrict__ out) {
  __shared__ SharedU sm;
  if (*flag)
    fused_impl<true>(sm, x, edge, bq, bk, bv, bo, Wbias, bbias, Wgate, bgate,
                     Wscale, bscale, Wshift, bshift, Whs, bhs, WT, out);
  else
    fused_impl<false>(sm, x, edge, bq, bk, bv, bo, Wbias, bbias, Wgate, bgate,
                      Wscale, bscale, Wshift, bshift, Whs, bhs, WT, out);
}

extern "C" void kernel_launch(void* const* d_in, const int* in_sizes, int n_in,
                              void* d_out, int out_size, void* d_ws, size_t ws_size,
                              hipStream_t stream) {
  (void)in_sizes; (void)n_in; (void)out_size; (void)ws_size;
  const void* x      = d_in[0];
  const void* edge   = d_in[1];
  const void* Wq     = d_in[2];  const void* bq  = d_in[3];
  const void* Wk     = d_in[4];  const void* bk  = d_in[5];
  const void* Wv     = d_in[6];  const void* bv  = d_in[7];
  const void* Wo     = d_in[8];  const void* bo  = d_in[9];
  const void* Wbias  = d_in[10]; const void* bbias  = d_in[11];
  const void* Wgate  = d_in[12]; const void* bgate  = d_in[13];
  const void* Wscale = d_in[14]; const void* bscale = d_in[15];
  const void* Wshift = d_in[16]; const void* bshift = d_in[17];
  const void* Whs    = d_in[18]; const void* bhs    = d_in[19];
  u16* WT   = (u16*)d_ws;
  int* flag = (int*)((char*)d_ws + WT_BYTES);
  float* out = (float*)d_out;

  prep_kernel<<<1024, 256, 0, stream>>>((const u16*)x, Wq, Wk, Wv, Wo, flag, WT);
  fused_kernel<<<2048, 256, 0, stream>>>(x, edge, bq, bk, bv, bo, Wbias, bbias,
                                         Wgate, bgate, Wscale, bscale, Wshift, bshift,
                                         Whs, bhs, flag, WT, out);
}

// Round 4
// 685.014 us; speedup vs baseline: 1.2826x; 1.2826x over previous
//
#include <hip/hip_runtime.h>

// GraphDiTPolicy fused kernel for MI355X (gfx950).
// B=32768, N=2, T=4, D=256, H=8, E=2, HD=32, S=8. Output FP32.
//
// Round 7 (theory: round-6's persistent fo[2][4]+wob registers pushed live
// state to ~190 VGPRs against a 128 budget -> compiler spilled them to
// scratch = +755MB writes/+550MB reads per dispatch. Fix: pooled goes back
// to LDS (costs occupancy, not HBM), sized to EXACTLY fit 3 blocks/CU):
//  - Scratch = qk 18432 + vt 14336 + pb 5120 + pooled[32][260] 16640
//    = 54528 B; 3x54528 = 163584 <= 163840 -> 3 blocks/CU (round-0's 54784
//    missed this by 512B and fell to 2).
//  - __launch_bounds__(256,3): VGPR budget ~168; in-loop peak (xa 64 +
//    acc 48 + temps) fits, no spill. Proj accumulators only live after the
//    head loop where xa/acc are dead.
//  - single kernel: out-projection at the end from pooled(LDS) @ WoT(L2),
//    plain fp32 stores (proven 66MB clean).
//  - keeps round-5 machinery: pipelined quarter staging via global_load_lds,
//    XOR-pre-swizzled WT, nontemporal x loads.

typedef short bf16x8 __attribute__((ext_vector_type(8)));
typedef float f32x4 __attribute__((ext_vector_type(4)));
typedef unsigned short u16;

#define SCALE_F 0.17677669529663687f   // 1/sqrt(32)
#define WT_BYTES (1024 * 256 * 2)      // (768+256) rows x 256 cols x 2B

__device__ __forceinline__ float bf2f(u16 h) {
  unsigned u = ((unsigned)h) << 16; float f; __builtin_memcpy(&f, &u, 4); return f;
}
__device__ __forceinline__ u16 f2bf(float f) {
  unsigned u; __builtin_memcpy(&u, &f, 4);
  u += 0x7FFFu + ((u >> 16) & 1u);
  return (u16)(u >> 16);
}
__device__ __forceinline__ float fast_tanh(float x) {
  float e = __expf(2.0f * x);
  return (e - 1.0f) / (e + 1.0f);
}

template<bool F32>
__device__ __forceinline__ float LD(const void* p, int i) {
  if constexpr (F32) return ((const float*)p)[i];
  else return bf2f(((const u16*)p)[i]);
}

// nontemporal 8-value bf16 A-fragment load (x is streamed once, no reuse)
template<bool F32>
__device__ __forceinline__ bf16x8 load8bf_nt(const void* p, int idx) {
  if constexpr (F32) {
    const f32x4* f = (const f32x4*)((const float*)p + idx);
    f32x4 a = __builtin_nontemporal_load(f);
    f32x4 b = __builtin_nontemporal_load(f + 1);
    bf16x8 r;
    r[0] = (short)f2bf(a[0]); r[1] = (short)f2bf(a[1]);
    r[2] = (short)f2bf(a[2]); r[3] = (short)f2bf(a[3]);
    r[4] = (short)f2bf(b[0]); r[5] = (short)f2bf(b[1]);
    r[6] = (short)f2bf(b[2]); r[7] = (short)f2bf(b[3]);
    return r;
  } else {
    return __builtin_nontemporal_load((const bf16x8*)((const u16*)p + idx));
  }
}

// async 16B global -> LDS (dest = wave-uniform base + lane*16)
__device__ __forceinline__ void gl_lds16(const u16* g, u16* l) {
  __builtin_amdgcn_global_load_lds(
      (const __attribute__((address_space(1))) unsigned int*)g,
      (__attribute__((address_space(3))) unsigned int*)l, 16, 0, 0);
}

// ---------------- prep: transpose weights to WT, compute dtype flag ----------
// WT[n][k'] rows 0-767 = {Wq,Wk,Wv} columns, XOR-pre-swizzled: k' = k ^ ((n&7)<<3)
// rows 768-1023 = Wo columns, UNswizzled (read as B-fragments directly).
__global__ void prep_kernel(const u16* __restrict__ x16,
                            const void* __restrict__ Wq, const void* __restrict__ Wk,
                            const void* __restrict__ Wv, const void* __restrict__ Wo,
                            int* __restrict__ flag, u16* __restrict__ WT) {
  __shared__ int tot;
  if (threadIdx.x == 0) tot = 0;
  __syncthreads();
  int cnt = 0;
  for (int i = threadIdx.x; i < 4096; i += 256) {
    int e = (x16[2 * i] >> 7) & 0xFF;
    cnt += (e >= 0x90 || e <= 0x50) ? 1 : 0;
  }
  atomicAdd(&tot, cnt);
  __syncthreads();
  const bool f32 = (tot >= 64);
  if (blockIdx.x == 0 && threadIdx.x == 0) *flag = f32 ? 1 : 0;

  int n = blockIdx.x;
  int k = threadIdx.x;
  if (n < 768) {
    int sel = n >> 8, col = n & 255;
    const void* src = sel == 0 ? Wq : (sel == 1 ? Wk : Wv);
    float v = f32 ? ((const float*)src)[k * 256 + col] : bf2f(((const u16*)src)[k * 256 + col]);
    WT[n * 256 + (k ^ ((n & 7) << 3))] = f2bf(v);
  } else {
    int col = n - 768;
    float v = f32 ? ((const float*)Wo)[k * 256 + col] : bf2f(((const u16*)Wo)[k * 256 + col]);
    WT[768 * 256 + col * 256 + k] = f2bf(v);
  }
}

// ---------------- main fused kernel -----------------------------------------
struct __align__(16) Scratch {
  u16 qk[4][32][72];    // [wave][xrow][Q 0-31 | K 32-63 | pad]          18432 B
  u16 vt[4][32][56];    // [wave][d][xrow]; cols>=32 don't-care          14336 B
  u16 pb[4][16][40];    // [wave][s'][t]; cols 16-31 MUST be 0            5120 B
  u16 pooled[32][260];  // [block row][dim]; stride 520B -> 2-way max    16640 B
};                      // total 54528 B; x3 = 163584 <= 160KiB -> 3 blocks/CU
union SharedU {
  u16 wtile[2][6144];   // 2 x (96 rows x 64 cols) = 24576 B staging window
  Scratch s;            // staging only overlaps qk + first 6144B of vt
};

template<bool F32>
__device__ __forceinline__ void fused_impl(
    SharedU& sm,
    const void* __restrict__ x, const void* __restrict__ edge,
    const void* __restrict__ bq, const void* __restrict__ bk, const void* __restrict__ bv,
    const void* __restrict__ bo,
    const void* __restrict__ Wbias, const void* __restrict__ bbias,
    const void* __restrict__ Wgate, const void* __restrict__ bgate,
    const void* __restrict__ Wscale, const void* __restrict__ bscale,
    const void* __restrict__ Wshift, const void* __restrict__ bshift,
    const void* __restrict__ Whs, const void* __restrict__ bhs,
    const u16* __restrict__ WT, float* __restrict__ out) {
  const int tid = threadIdx.x;
  const int w  = tid >> 6;     // wave 0..3, owns batches w*4..w*4+3
  const int l  = tid & 63;
  const int ln = l & 15;
  const int q4 = l >> 4;       // quad group 0..3

  // one-time zero: vt (pads must stay finite/zero; waves 2-3 never restaged)
  // + pb cols 16-31. pb [32768,37888) and pooled [37888,54528) both sit
  // above the 24576B staging window -> never clobbered.
  {
    u16* vz = &sm.s.vt[w][0][0];
#pragma unroll
    for (int i = 0; i < 28; ++i) vz[l + 64 * i] = 0;   // 32*56 = 1792
    u16* pz = &sm.s.pb[w][0][0];
#pragma unroll
    for (int i = 0; i < 10; ++i) pz[l + 64 * i] = 0;   // 16*40 = 640
  }

  // edge preload (constant indices only -> stays in VGPRs)
  float eA[4], eB[4];
#pragma unroll
  for (int i = 0; i < 4; ++i) {
    int gb = blockIdx.x * 16 + w * 4 + i;
    eA[i] = LD<F32>(edge, gb * 2);
    eB[i] = LD<F32>(edge, gb * 2 + 1);
  }

  // X rows as MFMA A-fragments: lane holds X[mt*16+ln][ks*32 + q4*8 + j]
  const int xbase = (blockIdx.x * 128 + w * 32) * 256;
  bf16x8 xa[2][8];
#pragma unroll
  for (int mt = 0; mt < 2; ++mt)
#pragma unroll
    for (int ks = 0; ks < 8; ++ks)
      xa[mt][ks] = load8bf_nt<F32>(x, xbase + (mt * 16 + ln) * 256 + ks * 32 + q4 * 8);

  // per-lane staging source bases: staged row r = i*32 + w*8 + (l>>3),
  // global WT row ng = ((r>>5)<<8) + h*32 + (r&31); col (l&7)*8 within quarter
  const u16* wsrc[3];
#pragma unroll
  for (int i = 0; i < 3; ++i) {
    int r = i * 32 + w * 8 + (l >> 3);
    int ngb = ((r >> 5) << 8) + (r & 31);
    wsrc[i] = WT + ngb * 256 + (l & 7) * 8;
  }
  // head-independent LDS fragment addressing (quarter layout: 64-col rows)
  int rowoff[6];
#pragma unroll
  for (int nt = 0; nt < 6; ++nt)
    rowoff[nt] = ((nt >> 1) * 32 + (nt & 1) * 16 + ln) * 64;
  const int swz = (ln & 7) << 3;   // matches prep's pre-swizzle ((n&7)<<3)

#pragma unroll 1
  for (int h = 0; h < 8; ++h) {
    // ---------- QKV GEMM head h: [32 rows] x [96 cols] x K=256 ----------
    f32x4 acc[2][6];
#pragma unroll
    for (int mt = 0; mt < 2; ++mt)
#pragma unroll
      for (int nt = 0; nt < 6; ++nt) acc[mt][nt] = (f32x4){0.f, 0.f, 0.f, 0.f};

    __syncthreads();   // prev head fully done with aliased scratch
#pragma unroll
    for (int i = 0; i < 3; ++i)
      gl_lds16(wsrc[i] + h * 8192, &sm.wtile[0][(i * 32 + w * 8) * 64]);
    __syncthreads();   // quarter 0 staged & visible
#pragma unroll
    for (int q = 0; q < 4; ++q) {
      if (q < 3) {     // prefetch next quarter into the other buffer
#pragma unroll
        for (int i = 0; i < 3; ++i)
          gl_lds16(wsrc[i] + h * 8192 + (q + 1) * 64,
                   &sm.wtile[(q + 1) & 1][(i * 32 + w * 8) * 64]);
      }
#pragma unroll
      for (int k2 = 0; k2 < 2; ++k2) {
        int cx = (k2 * 32 + q4 * 8) ^ swz;
        const u16* wq = &sm.wtile[q & 1][0];
#pragma unroll
        for (int nt = 0; nt < 6; ++nt) {
          bf16x8 bfr = *(const bf16x8*)(wq + rowoff[nt] + cx);
          acc[0][nt] = __builtin_amdgcn_mfma_f32_16x16x32_bf16(xa[0][q * 2 + k2], bfr, acc[0][nt], 0, 0, 0);
          acc[1][nt] = __builtin_amdgcn_mfma_f32_16x16x32_bf16(xa[1][q * 2 + k2], bfr, acc[1][nt], 0, 0, 0);
        }
      }
      __syncthreads();  // staged q+1 visible; epilogue must not race wtile
    }

    // ---------- epilogue: Q,K (+bias) row-major to LDS ----------
#pragma unroll
    for (int nt = 0; nt < 4; ++nt) {
      int cb = (nt & 1) * 16 + ln;                       // 0..31 within head
      float bias = LD<F32>((nt >> 1) ? bk : bq, h * 32 + cb);
      int col = (nt >> 1) * 32 + cb;                     // Q: 0-31, K: 32-63
#pragma unroll
      for (int mt = 0; mt < 2; ++mt)
#pragma unroll
        for (int r = 0; r < 4; ++r)
          sm.s.qk[w][mt * 16 + q4 * 4 + r][col] = f2bf(acc[mt][nt][r] + bias);
    }
    // ---------- epilogue: V with edge modulation, stored transposed ----------
#pragma unroll
    for (int nt = 4; nt < 6; ++nt) {
      int dg = h * 32 + (nt - 4) * 16 + ln;              // global dim
      float bvv = LD<F32>(bv, dg);
      float wg0 = LD<F32>(Wgate, dg),  wg1 = LD<F32>(Wgate, 256 + dg),  bg  = LD<F32>(bgate, dg);
      float ws0 = LD<F32>(Wscale, dg), ws1 = LD<F32>(Wscale, 256 + dg), bs  = LD<F32>(bscale, dg);
      float wf0 = LD<F32>(Wshift, dg), wf1 = LD<F32>(Wshift, 256 + dg), bsh = LD<F32>(bshift, dg);
#pragma unroll
      for (int mt = 0; mt < 2; ++mt) {
        float e0 = (q4 & 2) ? eA[mt * 2 + 1] : eA[mt * 2];
        float e1 = (q4 & 2) ? eB[mt * 2 + 1] : eB[mt * 2];
        float ga = 1.f / (1.f + __expf(-(e0 * wg0 + e1 * wg1 + bg)));
        float sc = fast_tanh(e0 * ws0 + e1 * ws1 + bs);
        float sh = e0 * wf0 + e1 * wf1 + bsh;
        u16 vv[4];
#pragma unroll
        for (int r = 0; r < 4; ++r) {
          float v = acc[mt][nt][r] + bvv;
          v = (v * (1.f + sc) + sh) * ga;
          vv[r] = f2bf(v);
        }
        ushort4 pk; pk.x = vv[0]; pk.y = vv[1]; pk.z = vv[2]; pk.w = vv[3];
        *(ushort4*)&sm.s.vt[w][(nt - 4) * 16 + ln][mt * 16 + q4 * 4] = pk;
      }
    }
    __asm__ volatile("" ::: "memory");  // wave-private LDS; DS ops in-order

    // ---------- attention: 2 batches packed per 16x16 tile ----------
    float wb0 = LD<F32>(Wbias, h), wb1 = LD<F32>(Wbias, 8 + h), bb  = LD<F32>(bbias, h);
    float wh0 = LD<F32>(Whs, h),   wh1 = LD<F32>(Whs, 8 + h),   bh_ = LD<F32>(bhs, h);
#pragma unroll
    for (int pair = 0; pair < 2; ++pair) {
      bf16x8 qa = *(const bf16x8*)&sm.s.qk[w][pair * 16 + ln][q4 * 8];       // Q rows
      bf16x8 kb = *(const bf16x8*)&sm.s.qk[w][pair * 16 + ln][32 + q4 * 8];  // K rows
      f32x4 z4 = {0.f, 0.f, 0.f, 0.f};
      f32x4 s = __builtin_amdgcn_mfma_f32_16x16x32_bf16(qa, kb, z4, 0, 0, 0);

      float e00 = eA[pair * 2],     e01 = eB[pair * 2];
      float e10 = eA[pair * 2 + 1], e11 = eB[pair * 2 + 1];
      float eb0 = e00 * wb0 + e01 * wb1 + bb;
      float eb1 = e10 * wb0 + e11 * wb1 + bb;
      float hs0 = fast_tanh(e00 * wh0 + e01 * wh1 + bh_);
      float hs1 = fast_tanh(e10 * wh0 + e11 * wh1 + bh_);
      int bj = ln >> 3;                       // column batch within pair
      float mult = SCALE_F * (1.f + (bj ? hs1 : hs0));
      float ebias = bj ? eb1 : eb0;
      int tl = ln & 7;
      bool valid = ((q4 >> 1) == bj);         // row batch == col batch
      float p[4];
#pragma unroll
      for (int r = 0; r < 4; ++r) {
        int sl = (q4 & 1) * 4 + r;            // s within batch
        p[r] = s[r] * mult + ((tl == (sl ^ 4)) ? ebias : 0.f);  // sparse bias
      }
      // softmax over t (8-lane groups)
#pragma unroll
      for (int r = 0; r < 4; ++r) {
        float m = p[r];
        m = fmaxf(m, __shfl_xor(m, 1));
        m = fmaxf(m, __shfl_xor(m, 2));
        m = fmaxf(m, __shfl_xor(m, 4));
        float e = __expf(p[r] - m);
        float su = e;
        su += __shfl_xor(su, 1);
        su += __shfl_xor(su, 2);
        su += __shfl_xor(su, 4);
        p[r] = e / su;
      }
#pragma unroll
      for (int r = 0; r < 4; ++r)
        sm.s.pb[w][q4 * 4 + r][ln] = valid ? f2bf(p[r]) : (u16)0;
      __asm__ volatile("" ::: "memory");

      // P.V via MFMA; lane's 4 C rows = one (batch,node)'s T rows -> free mean
      bf16x8 pa = *(const bf16x8*)&sm.s.pb[w][ln][q4 * 8];
#pragma unroll
      for (int nt = 0; nt < 2; ++nt) {
        bf16x8 vb = *(const bf16x8*)&sm.s.vt[w][nt * 16 + ln][pair * 16 + q4 * 8];
        f32x4 z = {0.f, 0.f, 0.f, 0.f};
        f32x4 o = __builtin_amdgcn_mfma_f32_16x16x32_bf16(pa, vb, z, 0, 0, 0);
        float pm = (o[0] + o[1] + o[2] + o[3]) * 0.25f;   // mean over T=4
        int prow = w * 8 + (pair * 2 + (q4 >> 1)) * 2 + (q4 & 1);
        sm.s.pooled[prow][h * 32 + nt * 16 + ln] = f2bf(pm);  // wave-private rows
      }
    }
  }

  // ---------- final projection: pooled[32][256] @ Wo + bo (fp32 out) ----------
  __syncthreads();
  const u16* WoT = WT + 768 * 256;
  f32x4 fo[2][4];
#pragma unroll
  for (int mt = 0; mt < 2; ++mt)
#pragma unroll
    for (int nt = 0; nt < 4; ++nt) fo[mt][nt] = (f32x4){0.f, 0.f, 0.f, 0.f};
#pragma unroll
  for (int ks = 0; ks < 8; ++ks) {
    bf16x8 af0 = *(const bf16x8*)&sm.s.pooled[ln][ks * 32 + q4 * 8];
    bf16x8 af1 = *(const bf16x8*)&sm.s.pooled[16 + ln][ks * 32 + q4 * 8];
#pragma unroll
    for (int ntw = 0; ntw < 4; ++ntw) {
      int nrow = w * 64 + ntw * 16 + ln;
      bf16x8 bfr = *(const bf16x8*)(WoT + nrow * 256 + ks * 32 + q4 * 8);
      fo[0][ntw] = __builtin_amdgcn_mfma_f32_16x16x32_bf16(af0, bfr, fo[0][ntw], 0, 0, 0);
      fo[1][ntw] = __builtin_amdgcn_mfma_f32_16x16x32_bf16(af1, bfr, fo[1][ntw], 0, 0, 0);
    }
  }
#pragma unroll
  for (int ntw = 0; ntw < 4; ++ntw) {
    int col = w * 64 + ntw * 16 + ln;
    float bias = LD<F32>(bo, col);
#pragma unroll
    for (int mt = 0; mt < 2; ++mt)
#pragma unroll
      for (int r = 0; r < 4; ++r) {
        int row = mt * 16 + q4 * 4 + r;       // block-local batch*2+node
        out[(blockIdx.x * 32 + row) * 256 + col] = fo[mt][ntw][r] + bias;
      }
  }
}

__global__ __launch_bounds__(256, 3) void fused_kernel(
    const void* __restrict__ x, const void* __restrict__ edge,
    const void* __restrict__ bq, const void* __restrict__ bk, const void* __restrict__ bv,
    const void* __restrict__ bo,
    const void* __restrict__ Wbias, const void* __restrict__ bbias,
    const void* __restrict__ Wgate, const void* __restrict__ bgate,
    const void* __restrict__ Wscale, const void* __restrict__ bscale,
    const void* __restrict__ Wshift, const void* __restrict__ bshift,
    const void* __restrict__ Whs, const void* __restrict__ bhs,
    const int* __restrict__ flag, const u16* __restrict__ WT, float* __restrict__ out) {
  __shared__ SharedU sm;
  if (*flag)
    fused_impl<true>(sm, x, edge, bq, bk, bv, bo, Wbias, bbias, Wgate, bgate,
                     Wscale, bscale, Wshift, bshift, Whs, bhs, WT, out);
  else
    fused_impl<false>(sm, x, edge, bq, bk, bv, bo, Wbias, bbias, Wgate, bgate,
                      Wscale, bscale, Wshift, bshift, Whs, bhs, WT, out);
}

extern "C" void kernel_launch(void* const* d_in, const int* in_sizes, int n_in,
                              void* d_out, int out_size, void* d_ws, size_t ws_size,
                              hipStream_t stream) {
  (void)in_sizes; (void)n_in; (void)out_size; (void)ws_size;
  const void* x      = d_in[0];
  const void* edge   = d_in[1];
  const void* Wq     = d_in[2];  const void* bq  = d_in[3];
  const void* Wk     = d_in[4];  const void* bk  = d_in[5];
  const void* Wv     = d_in[6];  const void* bv  = d_in[7];
  const void* Wo     = d_in[8];  const void* bo  = d_in[9];
  const void* Wbias  = d_in[10]; const void* bbias  = d_in[11];
  const void* Wgate  = d_in[12]; const void* bgate  = d_in[13];
  const void* Wscale = d_in[14]; const void* bscale = d_in[15];
  const void* Wshift = d_in[16]; const void* bshift = d_in[17];
  const void* Whs    = d_in[18]; const void* bhs    = d_in[19];
  u16* WT   = (u16*)d_ws;
  int* flag = (int*)((char*)d_ws + WT_BYTES);
  float* out = (float*)d_out;

  prep_kernel<<<1024, 256, 0, stream>>>((const u16*)x, Wq, Wk, Wv, Wo, flag, WT);
  fused_kernel<<<2048, 256, 0, stream>>>(x, edge, bq, bk, bv, bo, Wbias, bbias,
                                         Wgate, bgate, Wscale, bscale, Wshift, bshift,
                                         Whs, bhs, flag, WT, out);
}